// Round 3
// baseline (162.342 us; speedup 1.0000x reference)
//
#include <hip/hip_runtime.h>
#include <math.h>

// ---------------- problem constants ----------------
#define NVEC   32768      // B*H*W
#define NCODE  1024
#define DIM    64
#define NEL    2097152    // B*D*H*W

// ---------------- output offsets (floats) ----------------
#define O_Q     0
#define O_LOSS  2097152
#define O_IDX   2097153
#define O_PERP  2129921
#define O_NECS  2129922
#define O_EMAW  2130946
#define O_W     2196482

// ---------------- workspace offsets (4-byte units) ----------------
#define W_WT     0          // 65536  transposed weight [64][1024] fp32
#define W_SW2    65536      // 1024   (float, rounded from fp64)
#define W_IDX    66560      // 32768  (int)
#define W_CNT    99328      // 1024
#define W_DW     100352     // 65536
#define W_LOSS   165888     // 1

// =====================================================================
// kernel 0: transpose weight -> wT[64][1024]; wsq[c] = fl32(fp64 sum w^2)
// =====================================================================
__global__ __launch_bounds__(256)
void k_prep(const float* __restrict__ w, float* __restrict__ wT,
            float* __restrict__ wsq) {
    __shared__ float sh[64][65];
    int tid = threadIdx.x;
    int j0 = blockIdx.x * 64;
    for (int p = 0; p < 16; ++p) {
        int f = p * 256 + tid;
        int j = f >> 6, d = f & 63;
        sh[j][d] = w[(j0 + j) * 64 + d];
    }
    __syncthreads();
    for (int p = 0; p < 16; ++p) {
        int f = p * 256 + tid;
        int d = f >> 6, jj = f & 63;
        wT[d * 1024 + j0 + jj] = sh[jj][d];
    }
    if (tid < 64) {
        double s = 0.0;
        #pragma unroll
        for (int d = 0; d < 64; ++d) {
            double v = (double)sh[tid][d];
            s = fma(v, v, s);
        }
        wsq[j0 + tid] = (float)s;
    }
}

// =====================================================================
// kernel 1: emulate np fp32 scores + argmin.
//   score = fl32( fl32(rowsq[r] + wsq[c]) - 2*fl32(dot_exact) )
// dot/rowsq/wsq accumulated in fp64, rounded once to fp32 (err ~1e-10,
// far below the ulp(~64)=7.6e-6 grid the reference's rounding creates).
// block = 64 rows x all 1024 codes; 16x16 threads, 4x4 fp64 acc each.
// Ties (common after quantization) -> lowest code index (np.argmin).
// =====================================================================
__global__ __launch_bounds__(256, 2)
void k_dist(const float* __restrict__ x, const float* __restrict__ wT,
            const float* __restrict__ wsq,
            int* __restrict__ idx_int, float* __restrict__ out_idxf) {
    __shared__ float xs[64][64];    // [k][row]
    __shared__ float wsh[64][64];   // [k][code] (per chunk)
    __shared__ float rsq[64];       // fl32 row ||x||^2
    int tid = threadIdx.x;
    int tx = tid & 15, ty = tid >> 4;
    int rbase = blockIdx.x * 64;
    int b   = rbase >> 10;
    int hw0 = rbase & 1023;
    const float* xb = x + b * 65536 + hw0;

    // stage x tile: xs[d][r]
    for (int p = 0; p < 4; ++p) {
        int f = p * 256 + tid;
        int d = f >> 4, r4 = (f & 15) << 2;
        *(float4*)(&xs[d][r4]) = *(const float4*)(xb + d * 1024 + r4);
    }
    __syncthreads();
    if (tid < 64) {
        double s = 0.0;
        #pragma unroll
        for (int d = 0; d < 64; ++d) {
            double v = (double)xs[d][tid];
            s = fma(v, v, s);
        }
        rsq[tid] = (float)s;
    }

    float best[4];
    int   bidx[4];
    #pragma unroll
    for (int i = 0; i < 4; ++i) { best[i] = 3.4e38f; bidx[i] = 0; }

    for (int ch = 0; ch < 16; ++ch) {
        int cb = ch * 64;
        __syncthreads();   // orders wsh reuse; makes rsq visible on iter 0
        for (int p = 0; p < 4; ++p) {
            int f = p * 256 + tid;
            int k = f >> 4, c4 = (f & 15) << 2;
            *(float4*)(&wsh[k][c4]) = *(const float4*)(wT + k * 1024 + cb + c4);
        }
        __syncthreads();

        double acc[4][4];
        #pragma unroll
        for (int i = 0; i < 4; ++i)
            #pragma unroll
            for (int j = 0; j < 4; ++j) acc[i][j] = 0.0;

        for (int k = 0; k < 64; ++k) {
            float4 xa = *(float4*)&xs[k][ty * 4];
            float4 wb = *(float4*)&wsh[k][tx * 4];
            double xd[4] = {(double)xa.x, (double)xa.y, (double)xa.z, (double)xa.w};
            double wd[4] = {(double)wb.x, (double)wb.y, (double)wb.z, (double)wb.w};
            #pragma unroll
            for (int i = 0; i < 4; ++i)
                #pragma unroll
                for (int j = 0; j < 4; ++j)
                    acc[i][j] = fma(xd[i], wd[j], acc[i][j]);
        }

        #pragma unroll
        for (int j = 0; j < 4; ++j) {
            int c = cb + tx * 4 + j;
            float s2 = wsq[c];
            #pragma unroll
            for (int i = 0; i < 4; ++i) {
                float dotf = (float)acc[i][j];              // fl32(exact dot)
                float t1   = rsq[ty * 4 + i] + s2;          // fl32 add @ ~64
                float sc   = t1 - 2.0f * dotf;              // 2*dotf exact; fl32 sub
                if (sc < best[i]) { best[i] = sc; bidx[i] = c; }  // ascending c => first-min
            }
        }
    }

    // reduce across the 16 tx-lanes sharing each row (tie -> lower index)
    #pragma unroll
    for (int off = 1; off < 16; off <<= 1) {
        #pragma unroll
        for (int i = 0; i < 4; ++i) {
            float ov = __shfl_xor(best[i], off);
            int   oi = __shfl_xor(bidx[i], off);
            if (ov < best[i] || (ov == best[i] && oi < bidx[i])) {
                best[i] = ov; bidx[i] = oi;
            }
        }
    }
    if (tx == 0) {
        #pragma unroll
        for (int i = 0; i < 4; ++i) {
            int r = rbase + ty * 4 + i;
            idx_int[r]  = bidx[i];
            out_idxf[r] = (float)bidx[i];
        }
    }
}

// =====================================================================
// kernel 2: quantized output + loss + counts + dw (block = 64 vectors)
// =====================================================================
__global__ __launch_bounds__(256)
void k_quant(const float* __restrict__ x, const float* __restrict__ w,
             const int* __restrict__ idx_int, float* __restrict__ outq,
             float* __restrict__ counts, float* __restrict__ dw,
             float* __restrict__ loss) {
    __shared__ float xs[64][65];
    __shared__ int   idxl[64];
    __shared__ float red[4];
    int tid = threadIdx.x;
    int n0  = blockIdx.x * 64;
    int b   = n0 >> 10, hw0 = n0 & 1023;
    const float* xb = x + b * 65536 + hw0;

    if (tid < 64) {
        int id = idx_int[n0 + tid];
        idxl[tid] = id;
        atomicAdd(&counts[id], 1.0f);
    }
    for (int p = 0; p < 16; ++p) {
        int f = p * 256 + tid;
        int d = f >> 6, n = f & 63;
        xs[d][n] = xb[d * 1024 + n];
    }
    __syncthreads();

    float ll = 0.f;
    for (int p = 0; p < 16; ++p) {
        int f = p * 256 + tid;
        int d = f >> 6, n = f & 63;
        float q  = w[idxl[n] * 64 + d];
        float xv = xs[d][n];
        float dd = q - xv;
        ll += dd * dd;
        outq[b * 65536 + d * 1024 + hw0 + n] = q;
    }
    #pragma unroll
    for (int off = 32; off; off >>= 1) ll += __shfl_down(ll, off);
    if ((tid & 63) == 0) red[tid >> 6] = ll;
    __syncthreads();
    if (tid == 0) atomicAdd(loss, red[0] + red[1] + red[2] + red[3]);

    // dw: lane = d, one coalesced 256B atomic row per vector
    int wv = tid >> 6, lane = tid & 63;
    for (int v = 0; v < 16; ++v) {
        int n = wv * 16 + v;
        atomicAdd(&dw[idxl[n] * 64 + lane], xs[lane][n]);
    }
}

// =====================================================================
// kernel 3: finalize (single block, 1024 threads)
// =====================================================================
__global__ __launch_bounds__(1024)
void k_final(const float* __restrict__ ema_cs, const float* __restrict__ ema_w,
             const float* __restrict__ counts, const float* __restrict__ dw,
             const float* __restrict__ loss, float* __restrict__ out) {
    __shared__ float cs[1024];
    __shared__ float redA[16], redB[16];
    __shared__ float ntot_sh;
    int tid = threadIdx.x;

    float c    = counts[tid];
    float necs = 0.99f * ema_cs[tid] + 0.01f * c;
    out[O_NECS + tid] = necs;

    float p   = c * (1.0f / 32768.0f);
    float ent = -p * logf(p + 1e-10f);

    float s1 = necs, s2 = ent;
    #pragma unroll
    for (int off = 32; off; off >>= 1) {
        s1 += __shfl_down(s1, off);
        s2 += __shfl_down(s2, off);
    }
    int wv = tid >> 6;
    if ((tid & 63) == 0) { redA[wv] = s1; redB[wv] = s2; }
    __syncthreads();
    if (tid == 0) {
        float t1 = 0.f, t2 = 0.f;
        for (int i = 0; i < 16; ++i) { t1 += redA[i]; t2 += redB[i]; }
        ntot_sh = t1;
        out[O_PERP] = expf(t2);
        out[O_LOSS] = 0.25f * loss[0] * (1.0f / 2097152.0f);
    }
    __syncthreads();
    float ntot = ntot_sh;
    cs[tid] = (necs + 1e-5f) / (ntot + 1024.0f * 1e-5f) * ntot;
    __syncthreads();

    for (int pp = 0; pp < 64; ++pp) {
        int f = pp * 1024 + tid;
        int j = f >> 6;
        float ne = 0.99f * ema_w[f] + 0.01f * dw[f];
        out[O_EMAW + f] = ne;
        out[O_W + f]    = ne / cs[j];
    }
}

// =====================================================================
extern "C" void kernel_launch(void* const* d_in, const int* in_sizes, int n_in,
                              void* d_out, int out_size, void* d_ws, size_t ws_size,
                              hipStream_t stream) {
    const float* x      = (const float*)d_in[0];
    const float* w      = (const float*)d_in[1];
    const float* ema_cs = (const float*)d_in[2];
    const float* ema_w  = (const float*)d_in[3];
    float* out = (float*)d_out;
    float* ws  = (float*)d_ws;

    float* wT     = ws + W_WT;
    float* wsq    = ws + W_SW2;
    int*   idxi   = (int*)(ws + W_IDX);
    float* counts = ws + W_CNT;
    float* dwb    = ws + W_DW;
    float* lossb  = ws + W_LOSS;

    // zero counts + dw + loss every call (harness does not re-poison)
    hipMemsetAsync(ws + W_CNT, 0, (size_t)(1024 + 65536 + 1) * 4, stream);

    k_prep <<<16,  256, 0, stream>>>(w, wT, wsq);
    k_dist <<<512, 256, 0, stream>>>(x, wT, wsq, idxi, out + O_IDX);
    k_quant<<<512, 256, 0, stream>>>(x, w, idxi, out + O_Q, counts, dwb, lossb);
    k_final<<<1,  1024, 0, stream>>>(ema_cs, ema_w, counts, dwb, lossb, out);
}

// Round 4
// 94.499 us; speedup vs baseline: 1.7179x; 1.7179x over previous
//
#include <hip/hip_runtime.h>
#include <math.h>

// ---------------- output offsets (floats) ----------------
#define O_Q     0
#define O_LOSS  2097152
#define O_IDX   2097153
#define O_PERP  2129921
#define O_NECS  2129922
#define O_EMAW  2130946
#define O_W     2196482

// ---------------- workspace offsets (4-byte units) ----------------
#define W_WT     0          // 65536  transposed weight [64][1024] fp32
#define W_SW2    65536      // 1024   (float, rounded from fp64)
#define W_IDX    66560      // 32768  (int)
#define W_CNT    99328      // 1024
#define W_DW     100352     // 65536
#define W_LOSS   165888     // 1
#define W_CS     165952     // 1024

// =====================================================================
// kernel 0: transpose weight -> wT[64][1024]; wsq[c] = fl32(fp64 sum w^2)
// =====================================================================
__global__ __launch_bounds__(256)
void k_prep(const float* __restrict__ w, float* __restrict__ wT,
            float* __restrict__ wsq) {
    __shared__ float sh[64][65];
    int tid = threadIdx.x;
    int j0 = blockIdx.x * 64;
    for (int p = 0; p < 16; ++p) {
        int f = p * 256 + tid;
        int j = f >> 6, d = f & 63;
        sh[j][d] = w[(j0 + j) * 64 + d];
    }
    __syncthreads();
    for (int p = 0; p < 16; ++p) {
        int f = p * 256 + tid;
        int d = f >> 6, jj = f & 63;
        wT[d * 1024 + j0 + jj] = sh[jj][d];
    }
    if (tid < 64) {
        double s = 0.0;
        #pragma unroll
        for (int d = 0; d < 64; ++d) {
            double v = (double)sh[tid][d];
            s = fma(v, v, s);
        }
        wsq[j0 + tid] = (float)s;
    }
}

// =====================================================================
// kernel 1: fp32 scores + argmin, emulating np's fp32 expression tree:
//   score = fl32( fl32(rsq[r] + wsq[c]) - 2*dot_f32 )
// dot in plain fp32 FMA (error ~2e-9 ~= np sgemm's own error; the 7.6e-6
// score-quantization grid swamps it). rsq/wsq rounded once from fp64
// (per-row rsq errors are grid multiples -> argmin-invariant).
// tile: 128 rows x 256 codes/chunk, 4 chunks; 512 thr, 8x8 per thread.
// 256 blocks = 1/CU, 8 waves/CU. Ties -> lowest code index (np.argmin).
// =====================================================================
__global__ __launch_bounds__(512, 2)
void k_dist(const float* __restrict__ x, const float* __restrict__ wT,
            const float* __restrict__ wsq,
            int* __restrict__ idx_int, float* __restrict__ out_idxf) {
    __shared__ float xs[64][128];    // [k][row]   32 KB
    __shared__ float wsh[64][256];   // [k][code]  64 KB (per chunk)
    __shared__ float rsq[128];
    __shared__ float wsqs[256];
    int tid = threadIdx.x;
    int tx = tid & 31, ty = tid >> 5;       // tx: codes, ty: rows
    int rbase = blockIdx.x * 128;
    int b = rbase >> 10, hw0 = rbase & 1023;
    const float* xb = x + b * 65536 + hw0;

    // stage x tile: xs[d][r]
    for (int p = 0; p < 4; ++p) {
        int f = p * 512 + tid;
        int d = f >> 5, r4 = (f & 31) << 2;
        *(float4*)&xs[d][r4] = *(const float4*)(xb + d * 1024 + r4);
    }
    __syncthreads();
    if (tid < 128) {
        double s = 0.0;
        #pragma unroll
        for (int d = 0; d < 64; ++d) {
            double v = (double)xs[d][tid];
            s = fma(v, v, s);
        }
        rsq[tid] = (float)s;
    }

    float best[2][4];
    int   bidx[2][4];
    #pragma unroll
    for (int rp = 0; rp < 2; ++rp)
        #pragma unroll
        for (int i = 0; i < 4; ++i) { best[rp][i] = 3.4e38f; bidx[rp][i] = 0; }

    for (int ch = 0; ch < 4; ++ch) {
        int cb = ch * 256;
        __syncthreads();   // protect wsh reuse; orders rsq writes on ch==0
        for (int p = 0; p < 8; ++p) {
            int f = p * 512 + tid;
            int k = f >> 6, c4 = (f & 63) << 2;
            *(float4*)&wsh[k][c4] = *(const float4*)(wT + k * 1024 + cb + c4);
        }
        if (tid < 64) *(float4*)&wsqs[tid * 4] = *(const float4*)(wsq + cb + tid * 4);
        __syncthreads();

        float acc[2][2][4][4];
        #pragma unroll
        for (int rp = 0; rp < 2; ++rp)
            #pragma unroll
            for (int cp = 0; cp < 2; ++cp)
                #pragma unroll
                for (int i = 0; i < 4; ++i)
                    #pragma unroll
                    for (int j = 0; j < 4; ++j) acc[rp][cp][i][j] = 0.f;

        #pragma unroll 4
        for (int k = 0; k < 64; ++k) {
            float4 xa0 = *(float4*)&xs[k][ty * 4];
            float4 xa1 = *(float4*)&xs[k][64 + ty * 4];
            float4 wb0 = *(float4*)&wsh[k][tx * 4];
            float4 wb1 = *(float4*)&wsh[k][128 + tx * 4];
            float xr[2][4] = {{xa0.x, xa0.y, xa0.z, xa0.w},
                              {xa1.x, xa1.y, xa1.z, xa1.w}};
            float wc[2][4] = {{wb0.x, wb0.y, wb0.z, wb0.w},
                              {wb1.x, wb1.y, wb1.z, wb1.w}};
            #pragma unroll
            for (int rp = 0; rp < 2; ++rp)
                #pragma unroll
                for (int cp = 0; cp < 2; ++cp)
                    #pragma unroll
                    for (int i = 0; i < 4; ++i)
                        #pragma unroll
                        for (int j = 0; j < 4; ++j)
                            acc[rp][cp][i][j] += xr[rp][i] * wc[cp][j];
        }

        // score; iterate c ascending within thread => strict < keeps first min
        #pragma unroll
        for (int cp = 0; cp < 2; ++cp)
            #pragma unroll
            for (int j = 0; j < 4; ++j) {
                int cl = cp * 128 + tx * 4 + j;
                float s2 = wsqs[cl];
                int c = cb + cl;
                #pragma unroll
                for (int rp = 0; rp < 2; ++rp)
                    #pragma unroll
                    for (int i = 0; i < 4; ++i) {
                        float t1 = rsq[rp * 64 + ty * 4 + i] + s2;  // fl32 add @ ~64
                        float sc = t1 - 2.0f * acc[rp][cp][i][j];   // 2*dot exact; one rounding
                        if (sc < best[rp][i]) { best[rp][i] = sc; bidx[rp][i] = c; }
                    }
            }
    }

    // reduce across the 32 tx-lanes sharing each row (tie -> lower index)
    #pragma unroll
    for (int off = 1; off < 32; off <<= 1) {
        #pragma unroll
        for (int rp = 0; rp < 2; ++rp)
            #pragma unroll
            for (int i = 0; i < 4; ++i) {
                float ov = __shfl_xor(best[rp][i], off);
                int   oi = __shfl_xor(bidx[rp][i], off);
                if (ov < best[rp][i] ||
                    (ov == best[rp][i] && oi < bidx[rp][i])) {
                    best[rp][i] = ov; bidx[rp][i] = oi;
                }
            }
    }
    if (tx == 0) {
        #pragma unroll
        for (int rp = 0; rp < 2; ++rp)
            #pragma unroll
            for (int i = 0; i < 4; ++i) {
                int r = rbase + rp * 64 + ty * 4 + i;
                idx_int[r]  = bidx[rp][i];
                out_idxf[r] = (float)bidx[rp][i];
            }
    }
}

// =====================================================================
// kernel 2: quantized output + loss + counts + dw (block = 64 vectors)
// =====================================================================
__global__ __launch_bounds__(256)
void k_quant(const float* __restrict__ x, const float* __restrict__ w,
             const int* __restrict__ idx_int, float* __restrict__ outq,
             float* __restrict__ counts, float* __restrict__ dw,
             float* __restrict__ loss) {
    __shared__ float xs[64][65];
    __shared__ int   idxl[64];
    __shared__ float red[4];
    int tid = threadIdx.x;
    int n0  = blockIdx.x * 64;
    int b   = n0 >> 10, hw0 = n0 & 1023;
    const float* xb = x + b * 65536 + hw0;

    if (tid < 64) {
        int id = idx_int[n0 + tid];
        idxl[tid] = id;
        atomicAdd(&counts[id], 1.0f);
    }
    for (int p = 0; p < 16; ++p) {
        int f = p * 256 + tid;
        int d = f >> 6, n = f & 63;
        xs[d][n] = xb[d * 1024 + n];
    }
    __syncthreads();

    float ll = 0.f;
    for (int p = 0; p < 16; ++p) {
        int f = p * 256 + tid;
        int d = f >> 6, n = f & 63;
        float q  = w[idxl[n] * 64 + d];
        float xv = xs[d][n];
        float dd = q - xv;
        ll += dd * dd;
        outq[b * 65536 + d * 1024 + hw0 + n] = q;
    }
    #pragma unroll
    for (int off = 32; off; off >>= 1) ll += __shfl_down(ll, off);
    if ((tid & 63) == 0) red[tid >> 6] = ll;
    __syncthreads();
    if (tid == 0) atomicAdd(loss, red[0] + red[1] + red[2] + red[3]);

    // dw: lane = d, one coalesced 256B atomic row per vector
    int wv = tid >> 6, lane = tid & 63;
    for (int v = 0; v < 16; ++v) {
        int n = wv * 16 + v;
        atomicAdd(&dw[idxl[n] * 64 + lane], xs[lane][n]);
    }
}

// =====================================================================
// kernel 3a: scalars + cluster_size (single block, 1024 threads)
// =====================================================================
__global__ __launch_bounds__(1024)
void k_final_a(const float* __restrict__ ema_cs, const float* __restrict__ counts,
               const float* __restrict__ loss, float* __restrict__ cs_ws,
               float* __restrict__ out) {
    __shared__ float redA[16], redB[16];
    __shared__ float ntot_sh;
    int tid = threadIdx.x;

    float c    = counts[tid];
    float necs = 0.99f * ema_cs[tid] + 0.01f * c;
    out[O_NECS + tid] = necs;

    float p   = c * (1.0f / 32768.0f);
    float ent = -p * logf(p + 1e-10f);

    float s1 = necs, s2 = ent;
    #pragma unroll
    for (int off = 32; off; off >>= 1) {
        s1 += __shfl_down(s1, off);
        s2 += __shfl_down(s2, off);
    }
    int wv = tid >> 6;
    if ((tid & 63) == 0) { redA[wv] = s1; redB[wv] = s2; }
    __syncthreads();
    if (tid == 0) {
        float t1 = 0.f, t2 = 0.f;
        for (int i = 0; i < 16; ++i) { t1 += redA[i]; t2 += redB[i]; }
        ntot_sh = t1;
        out[O_PERP] = expf(t2);
        out[O_LOSS] = 0.25f * loss[0] * (1.0f / 2097152.0f);
    }
    __syncthreads();
    float ntot = ntot_sh;
    cs_ws[tid] = (necs + 1e-5f) / (ntot + 1024.0f * 1e-5f) * ntot;
}

// =====================================================================
// kernel 3b: EMA-w + new weight (256 blocks x 256 threads)
// =====================================================================
__global__ __launch_bounds__(256)
void k_final_b(const float* __restrict__ ema_w, const float* __restrict__ dw,
               const float* __restrict__ cs_ws, float* __restrict__ out) {
    int f = blockIdx.x * 256 + threadIdx.x;
    int j = f >> 6;
    float ne = 0.99f * ema_w[f] + 0.01f * dw[f];
    out[O_EMAW + f] = ne;
    out[O_W + f]    = ne / cs_ws[j];
}

// =====================================================================
extern "C" void kernel_launch(void* const* d_in, const int* in_sizes, int n_in,
                              void* d_out, int out_size, void* d_ws, size_t ws_size,
                              hipStream_t stream) {
    const float* x      = (const float*)d_in[0];
    const float* w      = (const float*)d_in[1];
    const float* ema_cs = (const float*)d_in[2];
    const float* ema_w  = (const float*)d_in[3];
    float* out = (float*)d_out;
    float* ws  = (float*)d_ws;

    float* wT     = ws + W_WT;
    float* wsq    = ws + W_SW2;
    int*   idxi   = (int*)(ws + W_IDX);
    float* counts = ws + W_CNT;
    float* dwb    = ws + W_DW;
    float* lossb  = ws + W_LOSS;
    float* cs_ws  = ws + W_CS;

    // zero counts + dw + loss every call (harness does not re-poison)
    hipMemsetAsync(ws + W_CNT, 0, (size_t)(1024 + 65536 + 1) * 4, stream);

    k_prep   <<<16,  256, 0, stream>>>(w, wT, wsq);
    k_dist   <<<256, 512, 0, stream>>>(x, wT, wsq, idxi, out + O_IDX);
    k_quant  <<<512, 256, 0, stream>>>(x, w, idxi, out + O_Q, counts, dwb, lossb);
    k_final_a<<<1,  1024, 0, stream>>>(ema_cs, counts, lossb, cs_ws, out);
    k_final_b<<<256, 256, 0, stream>>>(ema_w, dwb, cs_ws, out);
}